// Round 7
// baseline (292.560 us; speedup 1.0000x reference)
//
#include <hip/hip_runtime.h>
#include <hip/hip_bf16.h>

#define BSZ 8
#define CDIM 512
#define KDIM 512
#define HWSZ 16384   // 128*128
#define NPIX (BSZ*HWSZ)  // 131072

using bf16x8 = __attribute__((ext_vector_type(8))) short;
using f32x4  = __attribute__((ext_vector_type(4))) float;
typedef unsigned long long u64;

__device__ __forceinline__ unsigned pack2bf16(float lo, float hi) {
  // truncating f32->bf16 pair pack: lo -> bits[15:0], hi -> bits[31:16]
  return (__builtin_bit_cast(unsigned, lo) >> 16) |
         (__builtin_bit_cast(unsigned, hi) & 0xFFFF0000u);
}

// async global->LDS, 16B per lane; LDS dest = wave-uniform base + lane*16 (m104)
__device__ __forceinline__ void gload_lds16(const unsigned short* g, unsigned short* l) {
  __builtin_amdgcn_global_load_lds(
      (const __attribute__((address_space(1))) unsigned int*)g,
      (__attribute__((address_space(3))) unsigned int*)l, 16, 0, 0);
}

// ---------------- prep: Eb[k][c] = bf16( E[k][c] / ||E[k]|| ) ----------------
__global__ __launch_bounds__(64) void prep_emb_kernel(const float* __restrict__ E,
                                                      unsigned short* __restrict__ Eb) {
  int k = blockIdx.x;
  int lane = threadIdx.x;
  const float4* row = (const float4*)(E + (size_t)k * CDIM);
  float4 v0 = row[lane * 2], v1 = row[lane * 2 + 1];
  float ss = v0.x*v0.x + v0.y*v0.y + v0.z*v0.z + v0.w*v0.w
           + v1.x*v1.x + v1.y*v1.y + v1.z*v1.z + v1.w*v1.w;
  #pragma unroll
  for (int d = 1; d < 64; d <<= 1) ss += __shfl_xor(ss, d, 64);
  float rinv = rsqrtf(fmaxf(ss, 1e-24f));
  float f[8] = {v0.x, v0.y, v0.z, v0.w, v1.x, v1.y, v1.z, v1.w};
  unsigned o[8];
  #pragma unroll
  for (int e = 0; e < 8; ++e) {
    float x = f[e] * rinv;
    unsigned u = __builtin_bit_cast(unsigned, x);
    o[e] = (u + 0x7FFFu + ((u >> 16) & 1u)) >> 16;   // RNE f32->bf16
  }
  uint4 pack;
  pack.x = o[0] | (o[1] << 16);
  pack.y = o[2] | (o[3] << 16);
  pack.z = o[4] | (o[5] << 16);
  pack.w = o[6] | (o[7] << 16);
  ((uint4*)(Eb + (size_t)k * CDIM))[lane] = pack;
}

// ---------------- pass 1: Xt[px][c]=bf16(X[b][c][hw]) + fused ANN gt-count ----------------
// tile 64 px x 128 c; LDS rows = px (stride 65 u32: <=2-way banks both dirs).
// Each block also streams an 8192-float ANN chunk (exactly half a (b,k) slice).
__global__ __launch_bounds__(256) void transpose_gt_kernel(
    const float* __restrict__ X, const float* __restrict__ ANN,
    unsigned short* __restrict__ Xt, float* __restrict__ gt_count) {
  __shared__ unsigned int lds[64 * 65];
  __shared__ float sw[4];
  int t = threadIdx.x;
  int bid = blockIdx.x;
  int pb = bid & 2047, cb = bid >> 11;       // px-tile, c-block
  int px0 = pb * 64, c0 = cb * 128;
  int b = px0 >> 14, hw = px0 & (HWSZ - 1);
  int p = t & 15, cg = t >> 4;               // px-quad 0..15, c-group 0..15

  // X loads: 4 c-pairs (cg+16j), rows c and c+1, float4 over px (256B runs, 16 deep MLP)
  const float* xs = X + ((size_t)b * CDIM + c0) * HWSZ + hw + 4 * p;
  float4 v[8];
  #pragma unroll
  for (int j = 0; j < 4; ++j) {
    const float* s = xs + (size_t)(2 * (cg + 16 * j)) * HWSZ;
    v[2 * j]     = *(const float4*)s;
    v[2 * j + 1] = *(const float4*)(s + HWSZ);
  }
  // ANN stream (independent loads; fills the latency shadow)
  const float* Ap = ANN + (size_t)bid * 8192 + t * 4;
  float s0 = 0.f;
  #pragma unroll
  for (int r = 0; r < 8; ++r) {
    float4 a4 = *(const float4*)(Ap + r * 1024);
    s0 += (a4.x + a4.y) + (a4.z + a4.w);
  }
  // LDS transpose write: row = px-local, col = c-pair
  #pragma unroll
  for (int j = 0; j < 4; ++j) {
    float f0[4] = {v[2*j].x, v[2*j].y, v[2*j].z, v[2*j].w};
    float f1[4] = {v[2*j+1].x, v[2*j+1].y, v[2*j+1].z, v[2*j+1].w};
    #pragma unroll
    for (int jj = 0; jj < 4; ++jj)
      lds[(4 * p + jj) * 65 + cg + 16 * j] = pack2bf16(f0[jj], f1[jj]);
  }
  __syncthreads();
  // out: 1024 uint4-chunks; stride-65 rows aren't 16B-aligned -> 4x b32 reads per chunk
  #pragma unroll
  for (int k2 = 0; k2 < 4; ++k2) {
    int ch = t + 256 * k2;
    int px = ch >> 4, j = ch & 15;
    uint4 o;
    o.x = lds[px * 65 + 4 * j];
    o.y = lds[px * 65 + 4 * j + 1];
    o.z = lds[px * 65 + 4 * j + 2];
    o.w = lds[px * 65 + 4 * j + 3];
    *(uint4*)(Xt + (size_t)(px0 + px) * CDIM + c0 + 8 * j) = o;   // 256B runs / 4 px-rows
  }
  // gt_count: exact integer partials -> order-independent float atomics
  #pragma unroll
  for (int d = 1; d < 64; d <<= 1) s0 += __shfl_xor(s0, d, 64);
  if ((t & 63) == 0) sw[t >> 6] = s0;
  __syncthreads();
  if (t == 0) atomicAdd(&gt_count[(bid >> 1) & (KDIM - 1)], sw[0] + sw[1] + sw[2] + sw[3]);
}

// ---------------- pass 2: m97-style GEMM + per-class-block argmax -> u64 key atomicMax ----------------
// BM=128 px, BN=128 cls, BK=32; 256 thr = 4 waves (2 px-halves x 2 cls-halves),
// wave = 64px x 64cls, acc[4][4]=64 AGPR -> 4 blocks/CU. A,B via global_load_lds (linear LDS).
__global__ __launch_bounds__(256, 4) void gemm_argmax_kernel(
    const unsigned short* __restrict__ Xt, const unsigned short* __restrict__ Eb,
    u64* __restrict__ keys) {
  __shared__ unsigned short As[2][128 * 32];
  __shared__ unsigned short Bs[2][128 * 32];
  int t = threadIdx.x;
  int lane = t & 63;
  int wv = t >> 6;
  int p15 = lane & 15, q = lane >> 4;
  int wr = wv >> 1, wc = wv & 1;
  // XCD swizzle: 4096 blocks, 8 XCDs -> class-siblings stay on one XCD's L2
  int bid = (blockIdx.x & 7) * 512 + (blockIdx.x >> 3);
  int px0  = (bid >> 2) * 128;
  int cls0 = (bid & 3) * 128;

  // staging: per K-step 128 rows x 64 B for A and B = 512 chunks each; 2 per thread
  int ubase = (t & ~63) * 8;                 // wave-uniform LDS ushort offset (HW adds lane*16B)
  #define STAGE(buf, i)                                                              \
    {                                                                                \
      _Pragma("unroll")                                                              \
      for (int j = 0; j < 2; ++j) {                                                  \
        int ch = t + 256 * j;                                                        \
        int row = ch >> 2, q4 = ch & 3;                                              \
        gload_lds16(Xt + (size_t)(px0 + row) * CDIM + (i) * 32 + q4 * 8,             \
                    &As[buf][ubase + j * 2048]);                                     \
        gload_lds16(Eb + (size_t)(cls0 + row) * CDIM + (i) * 32 + q4 * 8,            \
                    &Bs[buf][ubase + j * 2048]);                                     \
      }                                                                              \
    }

  f32x4 acc[4][4];
  #pragma unroll
  for (int m = 0; m < 4; ++m)
    #pragma unroll
    for (int n = 0; n < 4; ++n)
      acc[m][n] = (f32x4){0.f, 0.f, 0.f, 0.f};

  STAGE(0, 0);
  for (int i = 0; i < 16; ++i) {
    int cur = i & 1;
    if (i < 15) STAGE(cur ^ 1, i + 1);
    __syncthreads();                          // drains gload_lds: buf[cur] ready
    bf16x8 a[4], bfr[4];
    #pragma unroll
    for (int m = 0; m < 4; ++m)               // wave's 16 b128s tile 1KB -> conflict-free
      a[m] = *(bf16x8*)&As[cur][(wr * 64 + m * 16 + p15) * 32 + q * 8];
    #pragma unroll
    for (int n = 0; n < 4; ++n)
      bfr[n] = *(bf16x8*)&Bs[cur][(wc * 64 + n * 16 + p15) * 32 + q * 8];
    #pragma unroll
    for (int n = 0; n < 4; ++n)
      #pragma unroll
      for (int m = 0; m < 4; ++m)
        acc[m][n] = __builtin_amdgcn_mfma_f32_16x16x32_bf16(a[m], bfr[n], acc[m][n], 0, 0, 0);
    __syncthreads();                          // reads done before next stage overwrites
  }
  #undef STAGE

  // argmax over this block's 128 cls; D layout: col(cls)=lane&15, row(px)=q*4+reg
  #pragma unroll
  for (int m = 0; m < 4; ++m) {
    #pragma unroll
    for (int r = 0; r < 4; ++r) {
      float best = acc[m][0][r];
      int bn = 0;
      #pragma unroll
      for (int n = 1; n < 4; ++n) {
        float v = acc[m][n][r];
        if (v > best) { best = v; bn = n; }
      }
      int bk = cls0 + wc * 64 + bn * 16 + p15;
      #pragma unroll
      for (int d = 1; d < 16; d <<= 1) {      // butterfly over 16 cls-col lanes
        float ov = __shfl_xor(best, d, 64);
        int   ok = __shfl_xor(bk, d, 64);
        if (ov > best || (ov == best && ok < bk)) { best = ov; bk = ok; }
      }
      if (p15 == 0) {
        int px = px0 + wr * 64 + m * 16 + q * 4 + r;
        unsigned u = __builtin_bit_cast(unsigned, best);
        unsigned ou = u ^ ((unsigned)((int)u >> 31) | 0x80000000u);  // order-preserving map
        u64 key = ((u64)ou << 32) | (unsigned)(511 - bk);            // tie -> min class
        atomicMax(&keys[px], key);
      }
    }
  }
}

// ---------------- pass 3: decode keys -> pred/inter counts ----------------
__global__ __launch_bounds__(256) void count_kernel(
    const u64* __restrict__ keys, const float* __restrict__ ANN,
    int* __restrict__ pred_count, int* __restrict__ inter) {
  int px = blockIdx.x * 256 + threadIdx.x;
  u64 key = keys[px];
  int cls = 511 - (int)(unsigned)(key & 0xFFFFFFFFull);
  atomicAdd(&pred_count[cls], 1);
  int b = px >> 14, hw = px & (HWSZ - 1);
  float g = ANN[((size_t)b * KDIM + cls) * HWSZ + hw];   // one-hot gather
  if (g > 0.5f) atomicAdd(&inter[cls], 1);
}

// ---------------- final dice reduction ----------------
__global__ __launch_bounds__(512) void final_kernel(
    const int* __restrict__ pred_count, const int* __restrict__ inter,
    const float* __restrict__ gt_count, float* __restrict__ out) {
  int k = threadIdx.x;
  float G = gt_count[k];
  float P = (float)pred_count[k];
  float I = (float)inter[k];
  float card  = P + G;
  float score = (2.f * I + 1e-4f) / fmaxf(card + 1e-4f, 1e-7f);
  float v = (G > 0.f) ? (1.f - score) : 0.f;
  #pragma unroll
  for (int d = 1; d < 64; d <<= 1) v += __shfl_xor(v, d, 64);
  __shared__ float sw[8];
  if ((k & 63) == 0) sw[k >> 6] = v;
  __syncthreads();
  if (k == 0) {
    float s = 0.f;
    #pragma unroll
    for (int i = 0; i < 8; ++i) s += sw[i];
    out[0] = s / (float)KDIM;
  }
}

// ---------------- fallback (only if ws too small): R1 one-pass + gt stream ----------------
__global__ __launch_bounds__(256) void gt_count_fb(const float* __restrict__ ANN,
                                                   float* __restrict__ gt_count) {
  int slice = blockIdx.x;
  int k = slice & (KDIM - 1);
  const float4* p = (const float4*)(ANN + (size_t)slice * HWSZ);
  float s = 0.f;
  #pragma unroll
  for (int i = 0; i < 16; ++i) {
    float4 v = p[threadIdx.x + i * 256];
    s += v.x + v.y + v.z + v.w;
  }
  #pragma unroll
  for (int d = 1; d < 64; d <<= 1) s += __shfl_xor(s, d, 64);
  __shared__ float sw[4];
  if ((threadIdx.x & 63) == 0) sw[threadIdx.x >> 6] = s;
  __syncthreads();
  if (threadIdx.x == 0) atomicAdd(&gt_count[k], sw[0] + sw[1] + sw[2] + sw[3]);
}

__global__ __launch_bounds__(256, 1) void gemm_fb(
    const float* __restrict__ X, const float* __restrict__ ANN,
    const unsigned short* __restrict__ Eb,
    int* __restrict__ pred_count, int* __restrict__ inter) {
  int tid = threadIdx.x;
  int wv = tid >> 6;
  int lane = tid & 63;
  int p15 = lane & 15, q = lane >> 4;
  int pix0 = blockIdx.x * 64;
  int b = pix0 >> 14;
  int hw = pix0 & (HWSZ - 1);
  const float*          Xb = X  + (size_t)b * CDIM * HWSZ + hw + p15;
  const unsigned short* Ew = Eb + (size_t)(wv * 128) * CDIM;
  f32x4 acc[4][8];
  #pragma unroll
  for (int m = 0; m < 4; ++m)
    #pragma unroll
    for (int n = 0; n < 8; ++n)
      acc[m][n] = (f32x4){0.f, 0.f, 0.f, 0.f};
  for (int cs = 0; cs < 16; ++cs) {
    int c0 = cs * 32 + q * 8;
    bf16x8 a[4];
    #pragma unroll
    for (int m = 0; m < 4; ++m)
      #pragma unroll
      for (int e = 0; e < 8; ++e) {
        float x = Xb[(size_t)(c0 + e) * HWSZ + m * 16];
        a[m][e] = (short)(__builtin_bit_cast(unsigned, x) >> 16);
      }
    bf16x8 bfrag[8];
    #pragma unroll
    for (int n = 0; n < 8; ++n)
      bfrag[n] = *(const bf16x8*)(Ew + (size_t)(n * 16 + p15) * CDIM + cs * 32 + q * 8);
    #pragma unroll
    for (int n = 0; n < 8; ++n)
      #pragma unroll
      for (int m = 0; m < 4; ++m)
        acc[m][n] = __builtin_amdgcn_mfma_f32_16x16x32_bf16(a[m], bfrag[n], acc[m][n], 0, 0, 0);
  }
  __shared__ float s_v[4][64];
  __shared__ int   s_k[4][64];
  #pragma unroll
  for (int m = 0; m < 4; ++m)
    #pragma unroll
    for (int r = 0; r < 4; ++r) {
      float best = acc[m][0][r];
      int bn = 0;
      #pragma unroll
      for (int n = 1; n < 8; ++n) {
        float v = acc[m][n][r];
        if (v > best) { best = v; bn = n; }
      }
      int bk = wv * 128 + bn * 16 + p15;
      #pragma unroll
      for (int d = 1; d < 16; d <<= 1) {
        float ov = __shfl_xor(best, d, 64);
        int   ok = __shfl_xor(bk, d, 64);
        if (ov > best || (ov == best && ok < bk)) { best = ov; bk = ok; }
      }
      if (p15 == 0) {
        int p = m * 16 + q * 4 + r;
        s_v[wv][p] = best;
        s_k[wv][p] = bk;
      }
    }
  __syncthreads();
  if (tid < 64) {
    int p = tid;
    float best = s_v[0][p]; int bk = s_k[0][p];
    #pragma unroll
    for (int w = 1; w < 4; ++w) {
      float v = s_v[w][p]; int kk = s_k[w][p];
      if (v > best || (v == best && kk < bk)) { best = v; bk = kk; }
    }
    atomicAdd(&pred_count[bk], 1);
    float g = ANN[((size_t)b * KDIM + bk) * HWSZ + hw + p];
    if (g > 0.5f) atomicAdd(&inter[bk], 1);
  }
}

extern "C" void kernel_launch(void* const* d_in, const int* in_sizes, int n_in,
                              void* d_out, int out_size, void* d_ws, size_t ws_size,
                              hipStream_t stream) {
  const float* X   = (const float*)d_in[0];   // [8,512,128,128] fp32
  const float* ANN = (const float*)d_in[1];   // [8,512,128,128] fp32 one-hot
  const float* E   = (const float*)d_in[2];   // [512,512] fp32

  char* base = (char*)d_ws;
  unsigned short* Eb = (unsigned short*)base;                  // 512 KiB @0
  float* gt_count    = (float*)(base + 524288);                // 2 KiB
  int*   pred_count  = (int*)  (base + 524288 + 2048);
  int*   inter       = (int*)  (base + 524288 + 4096);
  u64*   keys        = (u64*)  (base + 1048576);               // 1 MiB @1M
  unsigned short* Xt = (unsigned short*)(base + 2097152);      // 128 MiB @2M

  size_t need = 2097152 + (size_t)NPIX * CDIM * 2;

  prep_emb_kernel<<<KDIM, 64, 0, stream>>>(E, Eb);
  if (ws_size >= need) {
    hipMemsetAsync(base + 524288, 0, 1048576 + 524288 - 524288 + 1048576, stream); // [512K, 2M): counters+keys
    transpose_gt_kernel<<<8192, 256, 0, stream>>>(X, ANN, Xt, gt_count);
    gemm_argmax_kernel<<<4096, 256, 0, stream>>>(Xt, Eb, keys);
    count_kernel<<<NPIX / 256, 256, 0, stream>>>(keys, ANN, pred_count, inter);
  } else {
    hipMemsetAsync(base + 524288, 0, 6144, stream);
    gt_count_fb<<<BSZ * KDIM, 256, 0, stream>>>(ANN, gt_count);
    gemm_fb<<<NPIX / 64, 256, 0, stream>>>(X, ANN, Eb, pred_count, inter);
  }
  final_kernel<<<1, 512, 0, stream>>>(pred_count, inter, gt_count, (float*)d_out);
}

// Round 8
// 277.548 us; speedup vs baseline: 1.0541x; 1.0541x over previous
//
#include <hip/hip_runtime.h>
#include <hip/hip_bf16.h>

#define BSZ 8
#define CDIM 512
#define KDIM 512
#define HWSZ 16384   // 128*128
#define NPIX (BSZ*HWSZ)  // 131072

using bf16x8 = __attribute__((ext_vector_type(8))) short;
using f32x4  = __attribute__((ext_vector_type(4))) float;
typedef unsigned long long u64;

__device__ __forceinline__ unsigned pack2bf16(float lo, float hi) {
  // truncating f32->bf16 pair pack: lo -> bits[15:0], hi -> bits[31:16]
  return (__builtin_bit_cast(unsigned, lo) >> 16) |
         (__builtin_bit_cast(unsigned, hi) & 0xFFFF0000u);
}

// async global->LDS, 16B per lane; LDS dest = wave-uniform base + lane*16 (m104)
__device__ __forceinline__ void gload_lds16(const unsigned short* g, unsigned short* l) {
  __builtin_amdgcn_global_load_lds(
      (const __attribute__((address_space(1))) unsigned int*)g,
      (__attribute__((address_space(3))) unsigned int*)l, 16, 0, 0);
}

// ---------------- prep: Eb[k][c] = bf16( E[k][c] / ||E[k]|| ), plain + tiled ----------------
__global__ __launch_bounds__(64) void prep_emb_kernel(const float* __restrict__ E,
                                                      unsigned short* __restrict__ Eb,
                                                      unsigned short* __restrict__ EbT) {
  int k = blockIdx.x;
  int lane = threadIdx.x;
  const float4* row = (const float4*)(E + (size_t)k * CDIM);
  float4 v0 = row[lane * 2], v1 = row[lane * 2 + 1];
  float ss = v0.x*v0.x + v0.y*v0.y + v0.z*v0.z + v0.w*v0.w
           + v1.x*v1.x + v1.y*v1.y + v1.z*v1.z + v1.w*v1.w;
  #pragma unroll
  for (int d = 1; d < 64; d <<= 1) ss += __shfl_xor(ss, d, 64);
  float rinv = rsqrtf(fmaxf(ss, 1e-24f));
  float f[8] = {v0.x, v0.y, v0.z, v0.w, v1.x, v1.y, v1.z, v1.w};
  unsigned o[8];
  #pragma unroll
  for (int e = 0; e < 8; ++e) {
    float x = f[e] * rinv;
    unsigned u = __builtin_bit_cast(unsigned, x);
    o[e] = (u + 0x7FFFu + ((u >> 16) & 1u)) >> 16;   // RNE f32->bf16
  }
  uint4 pack;
  pack.x = o[0] | (o[1] << 16);
  pack.y = o[2] | (o[3] << 16);
  pack.z = o[4] | (o[5] << 16);
  pack.w = o[6] | (o[7] << 16);
  ((uint4*)(Eb + (size_t)k * CDIM))[lane] = pack;
  // tiled for GEMM staging: EbT[clsb][kstep][row][32c]; this lane covers c = lane*8..+7
  int clsb = k >> 7, rowi = k & 127, cs = lane >> 2, q4 = lane & 3;
  *(uint4*)(EbT + (size_t)clsb * 65536 + cs * 4096 + rowi * 32 + q4 * 8) = pack;
}

// ---------------- pass 1: X -> XtT (tiled bf16) + fused ANN gt-count ----------------
// tile 256 px x 64 c; every global instr (X read, ANN read, XtT store) = one 1KB run.
// LDS: 256 rows x 36 u32 (144B, 16B-aligned) -> b128 writes/reads, ~even banks.
__global__ __launch_bounds__(256) void transpose_gt_kernel(
    const float* __restrict__ X, const float* __restrict__ ANN,
    unsigned short* __restrict__ XtT, float* __restrict__ gt_count) {
  __shared__ unsigned int lds[256 * 36];
  __shared__ float swr[4];
  int t = threadIdx.x;
  int bid = blockIdx.x;
  int pt = bid & 511, cg = bid >> 9;       // px-tile 0..511, c-group 0..7 (64c each)
  int px0 = pt * 256, c0 = cg * 64;
  int b = px0 >> 14, hw = px0 & (HWSZ - 1);
  int w = t >> 6, lane = t & 63;

  const float* xb = X + ((size_t)b * CDIM + c0 + 16 * w) * HWSZ + hw + 4 * lane;
  const float* Ap = ANN + (size_t)bid * HWSZ + 4 * t;   // block == one (b,k) slice
  float s0 = 0.f;

  #pragma unroll
  for (int ph = 0; ph < 2; ++ph) {
    float4 xv[8];
    #pragma unroll
    for (int r = 0; r < 4; ++r) {          // rows 16w + 2*(4ph+r), +1  (1KB runs)
      int cc = 2 * (4 * ph + r);
      xv[2*r]   = *(const float4*)(xb + (size_t)cc * HWSZ);
      xv[2*r+1] = *(const float4*)(xb + (size_t)(cc + 1) * HWSZ);
    }
    #pragma unroll
    for (int r = 0; r < 8; ++r) {          // ANN stream (1KB runs)
      float4 a4 = *(const float4*)(Ap + (size_t)(8 * ph + r) * 1024);
      s0 += (a4.x + a4.y) + (a4.z + a4.w);
    }
    // pack + transpose write: thread covers px {4lane..4lane+3}, u32 cols 8w+4ph+{0..3}
    #pragma unroll
    for (int j = 0; j < 4; ++j) {
      unsigned pk[4];
      #pragma unroll
      for (int r = 0; r < 4; ++r)
        pk[r] = pack2bf16(((const float*)&xv[2*r])[j], ((const float*)&xv[2*r+1])[j]);
      *(uint4*)&lds[(size_t)(4 * lane + j) * 36 + 8 * w + 4 * ph] = *(const uint4*)pk;
    }
  }
  __syncthreads();
  // store 2048 16B-chunks in tiled order: consecutive lanes = consecutive (q4, px) -> 1KB runs
  #pragma unroll
  for (int rr = 0; rr < 8; ++rr) {
    int ch = rr * 256 + t;
    int q4 = ch & 3, px = (ch >> 2) & 255, s = ch >> 10;
    uint4 o = *(const uint4*)&lds[(size_t)px * 36 + s * 16 + q4 * 4];
    int pxg = px0 + px;
    int pxb = pxg >> 7, prow = pxg & 127;
    int ics = cg * 2 + s;                  // global k-step 0..15
    *(uint4*)(XtT + (size_t)(pxb * 16 + ics) * 4096 + prow * 32 + q4 * 8) = o;
  }
  // gt_count: exact integer partials -> order-independent float atomics
  #pragma unroll
  for (int d = 1; d < 64; d <<= 1) s0 += __shfl_xor(s0, d, 64);
  if (lane == 0) swr[w] = s0;
  __syncthreads();
  if (t == 0) atomicAdd(&gt_count[bid & (KDIM - 1)], swr[0] + swr[1] + swr[2] + swr[3]);
}

// ---------------- pass 2: m97-style GEMM + per-class-block argmax -> u64 key atomicMax ----------------
// BM=128 px, BN=128 cls, BK=32; 256 thr = 4 waves (2 px-halves x 2 cls-halves).
// Staging sources are pre-tiled -> each gload_lds wave-instr reads 4KB contiguous.
__global__ __launch_bounds__(256, 4) void gemm_argmax_kernel(
    const unsigned short* __restrict__ XtT, const unsigned short* __restrict__ EbT,
    u64* __restrict__ keys) {
  __shared__ unsigned short As[2][128 * 32];
  __shared__ unsigned short Bs[2][128 * 32];
  int t = threadIdx.x;
  int lane = t & 63;
  int wv = t >> 6;
  int p15 = lane & 15, q = lane >> 4;
  int wr = wv >> 1, wc = wv & 1;
  // XCD swizzle: class-siblings stay on one XCD's L2
  int bid = (blockIdx.x & 7) * 512 + (blockIdx.x >> 3);
  int pxb  = bid >> 2;
  int clsb = bid & 3;
  int px0  = pxb * 128;
  int cls0 = clsb * 128;

  const unsigned short* Abase = XtT + (size_t)pxb * 65536;   // 16 k-slabs x 4096 ushort
  const unsigned short* Bbase = EbT + (size_t)clsb * 65536;
  int ubase = (t & ~63) * 8;               // wave-uniform LDS ushort offset (HW adds lane*16B)
  #define STAGE(buf, i)                                                       \
    {                                                                         \
      _Pragma("unroll")                                                       \
      for (int j = 0; j < 2; ++j) {                                           \
        int ch = t + 256 * j;                                                 \
        gload_lds16(Abase + (size_t)(i) * 4096 + ch * 8, &As[buf][ubase + j * 2048]); \
        gload_lds16(Bbase + (size_t)(i) * 4096 + ch * 8, &Bs[buf][ubase + j * 2048]); \
      }                                                                       \
    }

  f32x4 acc[4][4];
  #pragma unroll
  for (int m = 0; m < 4; ++m)
    #pragma unroll
    for (int n = 0; n < 4; ++n)
      acc[m][n] = (f32x4){0.f, 0.f, 0.f, 0.f};

  STAGE(0, 0);
  for (int i = 0; i < 16; ++i) {
    int cur = i & 1;
    if (i < 15) STAGE(cur ^ 1, i + 1);
    __syncthreads();                          // drains gload_lds: buf[cur] ready
    bf16x8 a[4], bfr[4];
    #pragma unroll
    for (int m = 0; m < 4; ++m)               // wave's 16 b128s tile 1KB -> conflict-free
      a[m] = *(bf16x8*)&As[cur][(wr * 64 + m * 16 + p15) * 32 + q * 8];
    #pragma unroll
    for (int n = 0; n < 4; ++n)
      bfr[n] = *(bf16x8*)&Bs[cur][(wc * 64 + n * 16 + p15) * 32 + q * 8];
    #pragma unroll
    for (int n = 0; n < 4; ++n)
      #pragma unroll
      for (int m = 0; m < 4; ++m)
        acc[m][n] = __builtin_amdgcn_mfma_f32_16x16x32_bf16(a[m], bfr[n], acc[m][n], 0, 0, 0);
    __syncthreads();                          // reads done before next stage overwrites
  }
  #undef STAGE

  // argmax over this block's 128 cls; D layout: col(cls)=lane&15, row(px)=q*4+reg
  #pragma unroll
  for (int m = 0; m < 4; ++m) {
    #pragma unroll
    for (int r = 0; r < 4; ++r) {
      float best = acc[m][0][r];
      int bn = 0;
      #pragma unroll
      for (int n = 1; n < 4; ++n) {
        float v = acc[m][n][r];
        if (v > best) { best = v; bn = n; }
      }
      int bk = cls0 + wc * 64 + bn * 16 + p15;
      #pragma unroll
      for (int d = 1; d < 16; d <<= 1) {      // butterfly over 16 cls-col lanes
        float ov = __shfl_xor(best, d, 64);
        int   ok = __shfl_xor(bk, d, 64);
        if (ov > best || (ov == best && ok < bk)) { best = ov; bk = ok; }
      }
      if (p15 == 0) {
        int px = px0 + wr * 64 + m * 16 + q * 4 + r;
        unsigned u = __builtin_bit_cast(unsigned, best);
        unsigned ou = u ^ ((unsigned)((int)u >> 31) | 0x80000000u);  // order-preserving map
        u64 key = ((u64)ou << 32) | (unsigned)(511 - bk);            // tie -> min class
        atomicMax(&keys[px], key);
      }
    }
  }
}

// ---------------- pass 3: decode keys -> pred/inter counts ----------------
__global__ __launch_bounds__(256) void count_kernel(
    const u64* __restrict__ keys, const float* __restrict__ ANN,
    int* __restrict__ pred_count, int* __restrict__ inter) {
  int px = blockIdx.x * 256 + threadIdx.x;
  u64 key = keys[px];
  int cls = 511 - (int)(unsigned)(key & 0xFFFFFFFFull);
  atomicAdd(&pred_count[cls], 1);
  int b = px >> 14, hw = px & (HWSZ - 1);
  float g = ANN[((size_t)b * KDIM + cls) * HWSZ + hw];   // one-hot gather
  if (g > 0.5f) atomicAdd(&inter[cls], 1);
}

// ---------------- final dice reduction ----------------
__global__ __launch_bounds__(512) void final_kernel(
    const int* __restrict__ pred_count, const int* __restrict__ inter,
    const float* __restrict__ gt_count, float* __restrict__ out) {
  int k = threadIdx.x;
  float G = gt_count[k];
  float P = (float)pred_count[k];
  float I = (float)inter[k];
  float card  = P + G;
  float score = (2.f * I + 1e-4f) / fmaxf(card + 1e-4f, 1e-7f);
  float v = (G > 0.f) ? (1.f - score) : 0.f;
  #pragma unroll
  for (int d = 1; d < 64; d <<= 1) v += __shfl_xor(v, d, 64);
  __shared__ float sw[8];
  if ((k & 63) == 0) sw[k >> 6] = v;
  __syncthreads();
  if (k == 0) {
    float s = 0.f;
    #pragma unroll
    for (int i = 0; i < 8; ++i) s += sw[i];
    out[0] = s / (float)KDIM;
  }
}

// ---------------- fallback (only if ws too small): R1 one-pass + gt stream ----------------
__global__ __launch_bounds__(256) void gt_count_fb(const float* __restrict__ ANN,
                                                   float* __restrict__ gt_count) {
  int slice = blockIdx.x;
  int k = slice & (KDIM - 1);
  const float4* p = (const float4*)(ANN + (size_t)slice * HWSZ);
  float s = 0.f;
  #pragma unroll
  for (int i = 0; i < 16; ++i) {
    float4 v = p[threadIdx.x + i * 256];
    s += v.x + v.y + v.z + v.w;
  }
  #pragma unroll
  for (int d = 1; d < 64; d <<= 1) s += __shfl_xor(s, d, 64);
  __shared__ float sw[4];
  if ((threadIdx.x & 63) == 0) sw[threadIdx.x >> 6] = s;
  __syncthreads();
  if (threadIdx.x == 0) atomicAdd(&gt_count[k], sw[0] + sw[1] + sw[2] + sw[3]);
}

__global__ __launch_bounds__(256, 1) void gemm_fb(
    const float* __restrict__ X, const float* __restrict__ ANN,
    const unsigned short* __restrict__ Eb,
    int* __restrict__ pred_count, int* __restrict__ inter) {
  int tid = threadIdx.x;
  int wv = tid >> 6;
  int lane = tid & 63;
  int p15 = lane & 15, q = lane >> 4;
  int pix0 = blockIdx.x * 64;
  int b = pix0 >> 14;
  int hw = pix0 & (HWSZ - 1);
  const float*          Xb = X  + (size_t)b * CDIM * HWSZ + hw + p15;
  const unsigned short* Ew = Eb + (size_t)(wv * 128) * CDIM;
  f32x4 acc[4][8];
  #pragma unroll
  for (int m = 0; m < 4; ++m)
    #pragma unroll
    for (int n = 0; n < 8; ++n)
      acc[m][n] = (f32x4){0.f, 0.f, 0.f, 0.f};
  for (int cs = 0; cs < 16; ++cs) {
    int c0 = cs * 32 + q * 8;
    bf16x8 a[4];
    #pragma unroll
    for (int m = 0; m < 4; ++m)
      #pragma unroll
      for (int e = 0; e < 8; ++e) {
        float x = Xb[(size_t)(c0 + e) * HWSZ + m * 16];
        a[m][e] = (short)(__builtin_bit_cast(unsigned, x) >> 16);
      }
    bf16x8 bfrag[8];
    #pragma unroll
    for (int n = 0; n < 8; ++n)
      bfrag[n] = *(const bf16x8*)(Ew + (size_t)(n * 16 + p15) * CDIM + cs * 32 + q * 8);
    #pragma unroll
    for (int n = 0; n < 8; ++n)
      #pragma unroll
      for (int m = 0; m < 4; ++m)
        acc[m][n] = __builtin_amdgcn_mfma_f32_16x16x32_bf16(a[m], bfrag[n], acc[m][n], 0, 0, 0);
  }
  __shared__ float s_v[4][64];
  __shared__ int   s_k[4][64];
  #pragma unroll
  for (int m = 0; m < 4; ++m)
    #pragma unroll
    for (int r = 0; r < 4; ++r) {
      float best = acc[m][0][r];
      int bn = 0;
      #pragma unroll
      for (int n = 1; n < 8; ++n) {
        float v = acc[m][n][r];
        if (v > best) { best = v; bn = n; }
      }
      int bk = wv * 128 + bn * 16 + p15;
      #pragma unroll
      for (int d = 1; d < 16; d <<= 1) {
        float ov = __shfl_xor(best, d, 64);
        int   ok = __shfl_xor(bk, d, 64);
        if (ov > best || (ov == best && ok < bk)) { best = ov; bk = ok; }
      }
      if (p15 == 0) {
        int p = m * 16 + q * 4 + r;
        s_v[wv][p] = best;
        s_k[wv][p] = bk;
      }
    }
  __syncthreads();
  if (tid < 64) {
    int p = tid;
    float best = s_v[0][p]; int bk = s_k[0][p];
    #pragma unroll
    for (int w = 1; w < 4; ++w) {
      float v = s_v[w][p]; int kk = s_k[w][p];
      if (v > best || (v == best && kk < bk)) { best = v; bk = kk; }
    }
    atomicAdd(&pred_count[bk], 1);
    float g = ANN[((size_t)b * KDIM + bk) * HWSZ + hw + p];
    if (g > 0.5f) atomicAdd(&inter[bk], 1);
  }
}

extern "C" void kernel_launch(void* const* d_in, const int* in_sizes, int n_in,
                              void* d_out, int out_size, void* d_ws, size_t ws_size,
                              hipStream_t stream) {
  const float* X   = (const float*)d_in[0];   // [8,512,128,128] fp32
  const float* ANN = (const float*)d_in[1];   // [8,512,128,128] fp32 one-hot
  const float* E   = (const float*)d_in[2];   // [512,512] fp32

  char* base = (char*)d_ws;
  unsigned short* Eb  = (unsigned short*)base;                 // 512 KiB @0 (fallback)
  unsigned short* EbT = (unsigned short*)(base + 524288);      // 512 KiB @512K (tiled)
  float* gt_count     = (float*)(base + 1048576);              // 2 KiB
  int*   pred_count   = (int*)  (base + 1048576 + 2048);
  int*   inter        = (int*)  (base + 1048576 + 4096);
  u64*   keys         = (u64*)  (base + 1048576 + 8192);       // 1 MiB
  unsigned short* XtT = (unsigned short*)(base + 4194304);     // 134.2 MiB tiled bf16

  size_t need = 4194304 + (size_t)NPIX * CDIM * 2;

  prep_emb_kernel<<<KDIM, 64, 0, stream>>>(E, Eb, EbT);
  if (ws_size >= need) {
    hipMemsetAsync(base + 1048576, 0, 8192 + 1048576, stream);  // counters + keys
    transpose_gt_kernel<<<4096, 256, 0, stream>>>(X, ANN, XtT, gt_count);
    gemm_argmax_kernel<<<4096, 256, 0, stream>>>(XtT, EbT, keys);
    count_kernel<<<NPIX / 256, 256, 0, stream>>>(keys, ANN, pred_count, inter);
  } else {
    hipMemsetAsync(base + 1048576, 0, 6144, stream);
    gt_count_fb<<<BSZ * KDIM, 256, 0, stream>>>(ANN, gt_count);
    gemm_fb<<<NPIX / 64, 256, 0, stream>>>(X, ANN, Eb, pred_count, inter);
  }
  final_kernel<<<1, 512, 0, stream>>>(pred_count, inter, gt_count, (float*)d_out);
}